// Round 1
// baseline (135.318 us; speedup 1.0000x reference)
//
#include <hip/hip_runtime.h>
#include <hip/hip_bf16.h>

// Layout of the packed constant block (floats):
//  [0    .. 255]   Vr[16][16]   (Re of V = U * diag((-i)^popcount(col)))
//  [256  .. 511]   Vi[16][16]
//  [512  .. 767]   WpT[64][4]   (WpT[f][q] = Wp[q][f])
//  [768  .. 771]   bp[4]
//  [772  .. 1155]  MLP pack: per j in 0..63: {W1[j][0..3], b1[j], W2[j]}
//  [1156]          b2
#define CBUF_N 1157

__constant__ float CBUF[CBUF_N];

// ---------------- precompute: build V and pack weights into ws ----------------

__device__ inline void gate_rz(float* ar, float* ai, int q, float th) {
    float c = cosf(0.5f * th), s = sinf(0.5f * th);
    int st = 8 >> q;
    #pragma unroll
    for (int k = 0; k < 16; k++) {
        float r = ar[k], im = ai[k];
        if (k & st) {            // * e^{+i th/2}
            ar[k] = r * c - im * s;
            ai[k] = im * c + r * s;
        } else {                 // * e^{-i th/2}
            ar[k] = r * c + im * s;
            ai[k] = im * c - r * s;
        }
    }
}

__device__ inline void gate_ry(float* ar, float* ai, int q, float th) {
    float c = cosf(0.5f * th), s = sinf(0.5f * th);
    int st = 8 >> q;
    #pragma unroll
    for (int k = 0; k < 16; k++) {
        if (!(k & st)) {
            int k1 = k | st;
            float r0 = ar[k], i0 = ai[k], r1 = ar[k1], i1 = ai[k1];
            ar[k]  = c * r0 - s * r1;  ai[k]  = c * i0 - s * i1;
            ar[k1] = s * r0 + c * r1;  ai[k1] = s * i0 + c * i1;
        }
    }
}

__device__ inline void gate_cnot(float* ar, float* ai, int c, int t) {
    int stc = 8 >> c, stt = 8 >> t;
    #pragma unroll
    for (int k = 0; k < 16; k++) {
        if ((k & stc) && !(k & stt)) {
            int k1 = k | stt;
            float r = ar[k], im = ai[k];
            ar[k] = ar[k1]; ai[k] = ai[k1];
            ar[k1] = r;     ai[k1] = im;
        }
    }
}

__global__ void precompute_kernel(const float* __restrict__ Wp,
                                  const float* __restrict__ bp,
                                  const float* __restrict__ wq,
                                  const float* __restrict__ W1,
                                  const float* __restrict__ b1,
                                  const float* __restrict__ W2,
                                  const float* __restrict__ b2,
                                  float* __restrict__ ws) {
    int t = threadIdx.x;  // 64 threads

    if (t < 16) {
        // Simulate the fixed part of the circuit on basis state e_t -> column t of U.
        float ar[16], ai[16];
        #pragma unroll
        for (int k = 0; k < 16; k++) { ar[k] = 0.f; ai[k] = 0.f; }
        ar[t] = 1.f;

        for (int layer = 0; layer < 2; layer++) {
            for (int q = 0; q < 4; q++) {
                const float* w = &wq[(layer * 4 + q) * 3];
                gate_rz(ar, ai, q, w[0]);
                gate_ry(ar, ai, q, w[1]);
                gate_rz(ar, ai, q, w[2]);
            }
            for (int c = 0; c < 3; c++) gate_cnot(ar, ai, c, c + 1);
        }

        // fold phase (-i)^popcount(t) of the RX product state into column t
        int pc = __popc(t) & 3;
        #pragma unroll
        for (int j = 0; j < 16; j++) {
            float re = ar[j], im = ai[j], vr, vi;
            switch (pc) {
                case 0: vr = re;  vi = im;  break;
                case 1: vr = im;  vi = -re; break;   // *(-i)
                case 2: vr = -re; vi = -im; break;   // *(-1)
                case 3: vr = -im; vi = re;  break;   // *(+i)
            }
            ws[j * 16 + t]       = vr;
            ws[256 + j * 16 + t] = vi;
        }
    }

    // WpT pack: ws[512 + f*4 + q] = Wp[q*64 + f], f = t
    for (int q = 0; q < 4; q++) ws[512 + t * 4 + q] = Wp[q * 64 + t];
    if (t < 4) ws[768 + t] = bp[t];

    // MLP pack, row j = t
    ws[772 + t * 6 + 0] = W1[t * 4 + 0];
    ws[772 + t * 6 + 1] = W1[t * 4 + 1];
    ws[772 + t * 6 + 2] = W1[t * 4 + 2];
    ws[772 + t * 6 + 3] = W1[t * 4 + 3];
    ws[772 + t * 6 + 4] = b1[t];
    ws[772 + t * 6 + 5] = W2[t];
    if (t == 0) ws[1156] = b2[0];
}

// ---------------- main kernel: one thread per batch element ----------------

__global__ __launch_bounds__(256) void qmain_kernel(const float* __restrict__ x,
                                                    float* __restrict__ out,
                                                    int B) {
    int idx = blockIdx.x * 256 + threadIdx.x;
    if (idx >= B) return;

    // ---- angles = x[idx,:] @ Wp.T + bp ----
    const float4* x4 = reinterpret_cast<const float4*>(x) + idx * 16;
    float ang[4];
    #pragma unroll
    for (int q = 0; q < 4; q++) ang[q] = CBUF[768 + q];
    #pragma unroll
    for (int i = 0; i < 16; i++) {
        float4 v = x4[i];
        const float* w = &CBUF[512 + i * 16];
        #pragma unroll
        for (int q = 0; q < 4; q++) {
            ang[q] += v.x * w[q] + v.y * w[4 + q] + v.z * w[8 + q] + v.w * w[12 + q];
        }
    }

    // ---- RX product-state magnitudes m[16] ----
    float c[4], s[4];
    #pragma unroll
    for (int q = 0; q < 4; q++) {
        __sincosf(0.5f * ang[q], &s[q], &c[q]);
    }
    float pre[4]  = { c[0] * c[1], c[0] * s[1], s[0] * c[1], s[0] * s[1] };
    float post[4] = { c[2] * c[3], c[2] * s[3], s[2] * c[3], s[2] * s[3] };
    float m[16];
    #pragma unroll
    for (int k = 0; k < 16; k++) m[k] = pre[k >> 2] * post[k & 3];

    // ---- phi = V m ; p = |phi|^2 ; z = signed sums ----
    float z0 = 0.f, z1 = 0.f, z2 = 0.f, z3 = 0.f;
    #pragma unroll
    for (int j = 0; j < 16; j++) {
        const float* vr = &CBUF[j * 16];
        const float* vi = &CBUF[256 + j * 16];
        float re = 0.f, im = 0.f;
        #pragma unroll
        for (int k = 0; k < 16; k++) {
            re += vr[k] * m[k];
            im += vi[k] * m[k];
        }
        float p = re * re + im * im;
        z0 += (j & 8) ? -p : p;
        z1 += (j & 4) ? -p : p;
        z2 += (j & 2) ? -p : p;
        z3 += (j & 1) ? -p : p;
    }

    // ---- MLP: out = W2 @ relu(W1 @ z + b1) + b2 ----
    float acc = CBUF[1156];
    for (int j = 0; j < 64; j++) {
        const float* mp = &CBUF[772 + j * 6];
        float h = mp[4] + mp[0] * z0 + mp[1] * z1 + mp[2] * z2 + mp[3] * z3;
        h = fmaxf(h, 0.f);
        acc += mp[5] * h;
    }
    out[idx] = acc;
}

// ---------------- launch ----------------

extern "C" void kernel_launch(void* const* d_in, const int* in_sizes, int n_in,
                              void* d_out, int out_size, void* d_ws, size_t ws_size,
                              hipStream_t stream) {
    const float* x  = (const float*)d_in[0];
    const float* Wp = (const float*)d_in[1];
    const float* bp = (const float*)d_in[2];
    const float* wq = (const float*)d_in[3];
    const float* W1 = (const float*)d_in[4];
    const float* b1 = (const float*)d_in[5];
    const float* W2 = (const float*)d_in[6];
    const float* b2 = (const float*)d_in[7];
    float* ws = (float*)d_ws;
    float* out = (float*)d_out;

    int B = in_sizes[0] / 64;

    precompute_kernel<<<1, 64, 0, stream>>>(Wp, bp, wq, W1, b1, W2, b2, ws);

    void* sym = nullptr;
    hipGetSymbolAddress(&sym, HIP_SYMBOL(CBUF));
    hipMemcpyAsync(sym, ws, CBUF_N * sizeof(float), hipMemcpyDeviceToDevice, stream);

    int grid = (B + 255) / 256;
    qmain_kernel<<<grid, 256, 0, stream>>>(x, out, B);
}

// Round 2
// 133.098 us; speedup vs baseline: 1.0167x; 1.0167x over previous
//
#include <hip/hip_runtime.h>
#include <hip/hip_bf16.h>

// Packed parameter block in d_ws (floats):
//  [0    .. 255]   Vr[16][16]   (Re of V = U * diag((-i)^popcount(col)))
//  [256  .. 511]   Vi[16][16]
//  [512  .. 767]   WpT[64][4]   (WpT[f][q] = Wp[q][f])
//  [768  .. 771]   bp[4]
//  [772  .. 1155]  MLP pack: per j in 0..63: {W1[j][0..3], b1[j], W2[j]}
//  [1156]          b2
#define CBUF_N 1157

// ---------------- precompute: build V and pack weights into ws ----------------

__device__ inline void gate_rz(float* ar, float* ai, int q, float th) {
    float c = cosf(0.5f * th), s = sinf(0.5f * th);
    int st = 8 >> q;
    #pragma unroll
    for (int k = 0; k < 16; k++) {
        float r = ar[k], im = ai[k];
        if (k & st) {            // * e^{+i th/2}
            ar[k] = r * c - im * s;
            ai[k] = im * c + r * s;
        } else {                 // * e^{-i th/2}
            ar[k] = r * c + im * s;
            ai[k] = im * c - r * s;
        }
    }
}

__device__ inline void gate_ry(float* ar, float* ai, int q, float th) {
    float c = cosf(0.5f * th), s = sinf(0.5f * th);
    int st = 8 >> q;
    #pragma unroll
    for (int k = 0; k < 16; k++) {
        if (!(k & st)) {
            int k1 = k | st;
            float r0 = ar[k], i0 = ai[k], r1 = ar[k1], i1 = ai[k1];
            ar[k]  = c * r0 - s * r1;  ai[k]  = c * i0 - s * i1;
            ar[k1] = s * r0 + c * r1;  ai[k1] = s * i0 + c * i1;
        }
    }
}

__device__ inline void gate_cnot(float* ar, float* ai, int c, int t) {
    int stc = 8 >> c, stt = 8 >> t;
    #pragma unroll
    for (int k = 0; k < 16; k++) {
        if ((k & stc) && !(k & stt)) {
            int k1 = k | stt;
            float r = ar[k], im = ai[k];
            ar[k] = ar[k1]; ai[k] = ai[k1];
            ar[k1] = r;     ai[k1] = im;
        }
    }
}

__global__ void precompute_kernel(const float* __restrict__ Wp,
                                  const float* __restrict__ bp,
                                  const float* __restrict__ wq,
                                  const float* __restrict__ W1,
                                  const float* __restrict__ b1,
                                  const float* __restrict__ W2,
                                  const float* __restrict__ b2,
                                  float* __restrict__ ws) {
    int t = threadIdx.x;  // 64 threads

    if (t < 16) {
        // Simulate the fixed part of the circuit on basis state e_t -> column t of U.
        float ar[16], ai[16];
        #pragma unroll
        for (int k = 0; k < 16; k++) { ar[k] = 0.f; ai[k] = 0.f; }
        ar[t] = 1.f;

        for (int layer = 0; layer < 2; layer++) {
            for (int q = 0; q < 4; q++) {
                const float* w = &wq[(layer * 4 + q) * 3];
                gate_rz(ar, ai, q, w[0]);
                gate_ry(ar, ai, q, w[1]);
                gate_rz(ar, ai, q, w[2]);
            }
            for (int c = 0; c < 3; c++) gate_cnot(ar, ai, c, c + 1);
        }

        // fold phase (-i)^popcount(t) of the RX product state into column t
        int pc = __popc(t) & 3;
        #pragma unroll
        for (int j = 0; j < 16; j++) {
            float re = ar[j], im = ai[j], vr, vi;
            switch (pc) {
                case 0: vr = re;  vi = im;  break;
                case 1: vr = im;  vi = -re; break;   // *(-i)
                case 2: vr = -re; vi = -im; break;   // *(-1)
                case 3: vr = -im; vi = re;  break;   // *(+i)
            }
            ws[j * 16 + t]       = vr;
            ws[256 + j * 16 + t] = vi;
        }
    }

    // WpT pack: ws[512 + f*4 + q] = Wp[q*64 + f], f = t
    for (int q = 0; q < 4; q++) ws[512 + t * 4 + q] = Wp[q * 64 + t];
    if (t < 4) ws[768 + t] = bp[t];

    // MLP pack, row j = t
    ws[772 + t * 6 + 0] = W1[t * 4 + 0];
    ws[772 + t * 6 + 1] = W1[t * 4 + 1];
    ws[772 + t * 6 + 2] = W1[t * 4 + 2];
    ws[772 + t * 6 + 3] = W1[t * 4 + 3];
    ws[772 + t * 6 + 4] = b1[t];
    ws[772 + t * 6 + 5] = W2[t];
    if (t == 0) ws[1156] = b2[0];
}

// ---------------- main kernel: one thread per batch element ----------------
// cb = packed parameter block (wave-uniform, compile-time offsets -> s_load/K$)

__global__ __launch_bounds__(256) void qmain_kernel(const float* __restrict__ x,
                                                    const float* __restrict__ cb,
                                                    float* __restrict__ out,
                                                    int B) {
    int idx = blockIdx.x * 256 + threadIdx.x;
    if (idx >= B) return;

    // ---- angles = x[idx,:] @ Wp.T + bp ----
    const float4* x4 = reinterpret_cast<const float4*>(x) + idx * 16;
    float ang[4];
    #pragma unroll
    for (int q = 0; q < 4; q++) ang[q] = cb[768 + q];
    #pragma unroll
    for (int i = 0; i < 16; i++) {
        float4 v = x4[i];
        const float* w = &cb[512 + i * 16];
        #pragma unroll
        for (int q = 0; q < 4; q++) {
            ang[q] += v.x * w[q] + v.y * w[4 + q] + v.z * w[8 + q] + v.w * w[12 + q];
        }
    }

    // ---- RX product-state magnitudes m[16] ----
    float c[4], s[4];
    #pragma unroll
    for (int q = 0; q < 4; q++) {
        __sincosf(0.5f * ang[q], &s[q], &c[q]);
    }
    float pre[4]  = { c[0] * c[1], c[0] * s[1], s[0] * c[1], s[0] * s[1] };
    float post[4] = { c[2] * c[3], c[2] * s[3], s[2] * c[3], s[2] * s[3] };
    float m[16];
    #pragma unroll
    for (int k = 0; k < 16; k++) m[k] = pre[k >> 2] * post[k & 3];

    // ---- phi = V m ; p = |phi|^2 ; z = signed sums ----
    float z0 = 0.f, z1 = 0.f, z2 = 0.f, z3 = 0.f;
    #pragma unroll
    for (int j = 0; j < 16; j++) {
        const float* vr = &cb[j * 16];
        const float* vi = &cb[256 + j * 16];
        float re = 0.f, im = 0.f;
        #pragma unroll
        for (int k = 0; k < 16; k++) {
            re += vr[k] * m[k];
            im += vi[k] * m[k];
        }
        float p = re * re + im * im;
        z0 += (j & 8) ? -p : p;
        z1 += (j & 4) ? -p : p;
        z2 += (j & 2) ? -p : p;
        z3 += (j & 1) ? -p : p;
    }

    // ---- MLP: out = W2 @ relu(W1 @ z + b1) + b2 ----
    float acc = cb[1156];
    #pragma unroll
    for (int j = 0; j < 64; j++) {
        const float* mp = &cb[772 + j * 6];
        float h = mp[4] + mp[0] * z0 + mp[1] * z1 + mp[2] * z2 + mp[3] * z3;
        h = fmaxf(h, 0.f);
        acc += mp[5] * h;
    }
    out[idx] = acc;
}

// ---------------- launch ----------------

extern "C" void kernel_launch(void* const* d_in, const int* in_sizes, int n_in,
                              void* d_out, int out_size, void* d_ws, size_t ws_size,
                              hipStream_t stream) {
    const float* x  = (const float*)d_in[0];
    const float* Wp = (const float*)d_in[1];
    const float* bp = (const float*)d_in[2];
    const float* wq = (const float*)d_in[3];
    const float* W1 = (const float*)d_in[4];
    const float* b1 = (const float*)d_in[5];
    const float* W2 = (const float*)d_in[6];
    const float* b2 = (const float*)d_in[7];
    float* ws = (float*)d_ws;
    float* out = (float*)d_out;

    int B = in_sizes[0] / 64;

    precompute_kernel<<<1, 64, 0, stream>>>(Wp, bp, wq, W1, b1, W2, b2, ws);

    int grid = (B + 255) / 256;
    qmain_kernel<<<grid, 256, 0, stream>>>(x, ws, out, B);
}

// Round 3
// 124.564 us; speedup vs baseline: 1.0863x; 1.0685x over previous
//
#include <hip/hip_runtime.h>
#include <hip/hip_bf16.h>

// Packed parameter block in d_ws (floats):
//  [0    .. 255]   Vr[16][16]   (Re of V = U * diag((-i)^popcount(col)))
//  [256  .. 511]   Vi[16][16]
//  [512  .. 767]   WpT[64][4]   (WpT[f][q] = Wp[q][f])
//  [768  .. 771]   bp[4]
//  [772  .. 1155]  MLP pack: per j in 0..63: {W1[j][0..3], b1[j], W2[j]}
//  [1156]          b2
#define CBUF_N 1157

// ---------------- precompute: build V and pack weights into ws ----------------

__device__ inline void gate_rz(float* ar, float* ai, int q, float th) {
    float c = cosf(0.5f * th), s = sinf(0.5f * th);
    int st = 8 >> q;
    #pragma unroll
    for (int k = 0; k < 16; k++) {
        float r = ar[k], im = ai[k];
        if (k & st) {            // * e^{+i th/2}
            ar[k] = r * c - im * s;
            ai[k] = im * c + r * s;
        } else {                 // * e^{-i th/2}
            ar[k] = r * c + im * s;
            ai[k] = im * c - r * s;
        }
    }
}

__device__ inline void gate_ry(float* ar, float* ai, int q, float th) {
    float c = cosf(0.5f * th), s = sinf(0.5f * th);
    int st = 8 >> q;
    #pragma unroll
    for (int k = 0; k < 16; k++) {
        if (!(k & st)) {
            int k1 = k | st;
            float r0 = ar[k], i0 = ai[k], r1 = ar[k1], i1 = ai[k1];
            ar[k]  = c * r0 - s * r1;  ai[k]  = c * i0 - s * i1;
            ar[k1] = s * r0 + c * r1;  ai[k1] = s * i0 + c * i1;
        }
    }
}

__device__ inline void gate_cnot(float* ar, float* ai, int c, int t) {
    int stc = 8 >> c, stt = 8 >> t;
    #pragma unroll
    for (int k = 0; k < 16; k++) {
        if ((k & stc) && !(k & stt)) {
            int k1 = k | stt;
            float r = ar[k], im = ai[k];
            ar[k] = ar[k1]; ai[k] = ai[k1];
            ar[k1] = r;     ai[k1] = im;
        }
    }
}

__global__ void precompute_kernel(const float* __restrict__ Wp,
                                  const float* __restrict__ bp,
                                  const float* __restrict__ wq,
                                  const float* __restrict__ W1,
                                  const float* __restrict__ b1,
                                  const float* __restrict__ W2,
                                  const float* __restrict__ b2,
                                  float* __restrict__ ws) {
    int t = threadIdx.x;  // 64 threads

    if (t < 16) {
        // Simulate the fixed part of the circuit on basis state e_t -> column t of U.
        float ar[16], ai[16];
        #pragma unroll
        for (int k = 0; k < 16; k++) { ar[k] = 0.f; ai[k] = 0.f; }
        ar[t] = 1.f;

        for (int layer = 0; layer < 2; layer++) {
            for (int q = 0; q < 4; q++) {
                const float* w = &wq[(layer * 4 + q) * 3];
                gate_rz(ar, ai, q, w[0]);
                gate_ry(ar, ai, q, w[1]);
                gate_rz(ar, ai, q, w[2]);
            }
            for (int c = 0; c < 3; c++) gate_cnot(ar, ai, c, c + 1);
        }

        // fold phase (-i)^popcount(t) of the RX product state into column t
        int pc = __popc(t) & 3;
        #pragma unroll
        for (int j = 0; j < 16; j++) {
            float re = ar[j], im = ai[j], vr, vi;
            switch (pc) {
                case 0: vr = re;  vi = im;  break;
                case 1: vr = im;  vi = -re; break;   // *(-i)
                case 2: vr = -re; vi = -im; break;   // *(-1)
                case 3: vr = -im; vi = re;  break;   // *(+i)
            }
            ws[j * 16 + t]       = vr;
            ws[256 + j * 16 + t] = vi;
        }
    }

    // WpT pack: ws[512 + f*4 + q] = Wp[q*64 + f], f = t
    for (int q = 0; q < 4; q++) ws[512 + t * 4 + q] = Wp[q * 64 + t];
    if (t < 4) ws[768 + t] = bp[t];

    // MLP pack, row j = t
    ws[772 + t * 6 + 0] = W1[t * 4 + 0];
    ws[772 + t * 6 + 1] = W1[t * 4 + 1];
    ws[772 + t * 6 + 2] = W1[t * 4 + 2];
    ws[772 + t * 6 + 3] = W1[t * 4 + 3];
    ws[772 + t * 6 + 4] = b1[t];
    ws[772 + t * 6 + 5] = W2[t];
    if (t == 0) ws[1156] = b2[0];
}

// ---------------- main kernel ----------------
// Block = 256 threads = 256 rows. x is staged through LDS in two 32-column
// stages so every global load covers 8 FULL 128-B lines (8 consecutive lanes
// fetch one half-row). LDS row stride = 33 floats (odd) -> bank=(row+col)%32,
// <=2-way aliasing (free). b32 LDS ops because odd stride breaks 16-B align.

__global__ __launch_bounds__(256) void qmain_kernel(const float* __restrict__ x,
                                                    const float* __restrict__ cb,
                                                    float* __restrict__ out,
                                                    int B) {
    __shared__ float tile[256 * 33];
    const int t = threadIdx.x;
    const long row0 = (long)blockIdx.x * 256;
    const float* xb = x + row0 * 64;

    float ang[4];
    #pragma unroll
    for (int q = 0; q < 4; q++) ang[q] = cb[768 + q];

    #pragma unroll
    for (int s = 0; s < 2; s++) {
        if (s) __syncthreads();          // all reads of stage 0 done before overwrite
        // cooperative coalesced load: 256 rows x cols [s*32, s*32+32)
        #pragma unroll
        for (int r = 0; r < 8; r++) {
            int idx = r * 1024 + t * 4;  // float index into 256x32 submatrix
            int row = idx >> 5;
            int col = idx & 31;
            float4 v = *reinterpret_cast<const float4*>(xb + row * 64 + s * 32 + col);
            float* dst = &tile[row * 33 + col];
            dst[0] = v.x; dst[1] = v.y; dst[2] = v.z; dst[3] = v.w;
        }
        __syncthreads();
        const float* myrow = &tile[t * 33];
        #pragma unroll
        for (int i = 0; i < 32; i++) {
            float xv = myrow[i];
            const float* w = &cb[512 + (s * 32 + i) * 4];
            #pragma unroll
            for (int q = 0; q < 4; q++) ang[q] = fmaf(xv, w[q], ang[q]);
        }
    }

    // ---- RX product-state magnitudes m[16] ----
    float c[4], s4[4];
    #pragma unroll
    for (int q = 0; q < 4; q++) {
        __sincosf(0.5f * ang[q], &s4[q], &c[q]);
    }
    float pre[4]  = { c[0] * c[1], c[0] * s4[1], s4[0] * c[1], s4[0] * s4[1] };
    float post[4] = { c[2] * c[3], c[2] * s4[3], s4[2] * c[3], s4[2] * s4[3] };
    float m[16];
    #pragma unroll
    for (int k = 0; k < 16; k++) m[k] = pre[k >> 2] * post[k & 3];

    // ---- phi = V m ; p = |phi|^2 ; z = signed sums ----
    float z0 = 0.f, z1 = 0.f, z2 = 0.f, z3 = 0.f;
    #pragma unroll
    for (int j = 0; j < 16; j++) {
        const float* vr = &cb[j * 16];
        const float* vi = &cb[256 + j * 16];
        float re = 0.f, im = 0.f;
        #pragma unroll
        for (int k = 0; k < 16; k++) {
            re = fmaf(vr[k], m[k], re);
            im = fmaf(vi[k], m[k], im);
        }
        float p = re * re + im * im;
        z0 += (j & 8) ? -p : p;
        z1 += (j & 4) ? -p : p;
        z2 += (j & 2) ? -p : p;
        z3 += (j & 1) ? -p : p;
    }

    // ---- MLP: out = W2 @ relu(W1 @ z + b1) + b2 ----
    float acc = cb[1156];
    #pragma unroll
    for (int j = 0; j < 64; j++) {
        const float* mp = &cb[772 + j * 6];
        float h = mp[4];
        h = fmaf(mp[0], z0, h);
        h = fmaf(mp[1], z1, h);
        h = fmaf(mp[2], z2, h);
        h = fmaf(mp[3], z3, h);
        h = fmaxf(h, 0.f);
        acc = fmaf(mp[5], h, acc);
    }
    out[row0 + t] = acc;
}

// ---------------- launch ----------------

extern "C" void kernel_launch(void* const* d_in, const int* in_sizes, int n_in,
                              void* d_out, int out_size, void* d_ws, size_t ws_size,
                              hipStream_t stream) {
    const float* x  = (const float*)d_in[0];
    const float* Wp = (const float*)d_in[1];
    const float* bp = (const float*)d_in[2];
    const float* wq = (const float*)d_in[3];
    const float* W1 = (const float*)d_in[4];
    const float* b1 = (const float*)d_in[5];
    const float* W2 = (const float*)d_in[6];
    const float* b2 = (const float*)d_in[7];
    float* ws = (float*)d_ws;
    float* out = (float*)d_out;

    int B = in_sizes[0] / 64;

    precompute_kernel<<<1, 64, 0, stream>>>(Wp, bp, wq, W1, b1, W2, b2, ws);

    int grid = (B + 255) / 256;   // 1024 blocks, 256 rows each
    qmain_kernel<<<grid, 256, 0, stream>>>(x, ws, out, B);
}